// Round 1
// baseline (2731.509 us; speedup 1.0000x reference)
//
#include <hip/hip_runtime.h>

#define NTRAIN 65536
#define DIM    512
#define NQ     2048
#define KNN    5

#define QT 64            // queries per block tile
#define TT 64            // train points per sub-tile
#define KT 32            // K staging depth
#define NCHUNK 32        // train chunks (grid.y)
#define CHUNK (NTRAIN / NCHUNK)   // 2048
#define NQT (NQ / QT)             // 32

// ---------------- kernel A: t2[n] = sum(x_train[n,:]^2) ----------------
__global__ __launch_bounds__(256)
void t2_kernel(const float* __restrict__ xt, float* __restrict__ t2) {
    int row  = blockIdx.x * 4 + (threadIdx.x >> 6);
    int lane = threadIdx.x & 63;
    const float4* p = (const float4*)(xt + (size_t)row * DIM);
    float s = 0.f;
#pragma unroll
    for (int c = 0; c < 2; ++c) {
        float4 v = p[lane + c * 64];
        s += v.x * v.x + v.y * v.y + v.z * v.z + v.w * v.w;
    }
#pragma unroll
    for (int off = 32; off; off >>= 1) s += __shfl_down(s, off);
    if (lane == 0) t2[row] = s;
}

// ---------------- kernel B: fused GEMM + per-chunk top-5 ----------------
// score = t2[t] - 2 * dot(x[q], xt[t])   (rank-equivalent to d2)
__global__ __launch_bounds__(256)
void knn_partial(const float* __restrict__ x, const float* __restrict__ xt,
                 const float* __restrict__ t2,
                 float* __restrict__ candD, int* __restrict__ candI) {
    // staging (Xs,Ts) and merge (MD,MI) alias the same LDS
    __shared__ __align__(16) float smem[QT * 81 * 2];           // 41472 B
    float (*Xs)[QT + 4] = (float (*)[QT + 4])smem;              // [KT][68]
    float (*Ts)[TT + 4] = (float (*)[TT + 4])(smem + KT * (QT + 4));
    float (*MD)[81]     = (float (*)[81])smem;                  // [QT][81]
    int   (*MI)[81]     = (int   (*)[81])(smem + QT * 81);

    const int tid = threadIdx.x;
    const int tx = tid & 15, ty = tid >> 4;     // 16 x 16 thread tile
    const int q0 = blockIdx.x * QT;
    const int c0 = blockIdx.y * CHUNK;
    const int sq = tid >> 2, sc = tid & 3;      // staging map

    float bd[4][KNN]; int bi_[4][KNN];
#pragma unroll
    for (int i = 0; i < 4; ++i)
#pragma unroll
        for (int k = 0; k < KNN; ++k) { bd[i][k] = 3.4e38f; bi_[i][k] = 0x7fffffff; }

    const float* xrow = x + (size_t)(q0 + sq) * DIM;

    for (int s = 0; s < CHUNK; s += TT) {
        float acc[4][4];
#pragma unroll
        for (int i = 0; i < 4; ++i)
#pragma unroll
            for (int j = 0; j < 4; ++j) acc[i][j] = 0.f;

        const float* trow = xt + (size_t)(c0 + s + sq) * DIM;

        for (int kt = 0; kt < DIM; kt += KT) {
            float4 xv0 = *(const float4*)(xrow + kt + sc * 8);
            float4 xv1 = *(const float4*)(xrow + kt + sc * 8 + 4);
            float4 tv0 = *(const float4*)(trow + kt + sc * 8);
            float4 tv1 = *(const float4*)(trow + kt + sc * 8 + 4);
            __syncthreads();   // previous iter's reads complete before overwrite
            Xs[sc*8+0][sq] = xv0.x; Xs[sc*8+1][sq] = xv0.y;
            Xs[sc*8+2][sq] = xv0.z; Xs[sc*8+3][sq] = xv0.w;
            Xs[sc*8+4][sq] = xv1.x; Xs[sc*8+5][sq] = xv1.y;
            Xs[sc*8+6][sq] = xv1.z; Xs[sc*8+7][sq] = xv1.w;
            Ts[sc*8+0][sq] = tv0.x; Ts[sc*8+1][sq] = tv0.y;
            Ts[sc*8+2][sq] = tv0.z; Ts[sc*8+3][sq] = tv0.w;
            Ts[sc*8+4][sq] = tv1.x; Ts[sc*8+5][sq] = tv1.y;
            Ts[sc*8+6][sq] = tv1.z; Ts[sc*8+7][sq] = tv1.w;
            __syncthreads();
#pragma unroll
            for (int k = 0; k < KT; ++k) {
                const float4 av = *(const float4*)&Xs[k][ty * 4];
                const float4 bv = *(const float4*)&Ts[k][tx * 4];
                float a[4] = {av.x, av.y, av.z, av.w};
                float b[4] = {bv.x, bv.y, bv.z, bv.w};
#pragma unroll
                for (int i = 0; i < 4; ++i)
#pragma unroll
                    for (int j = 0; j < 4; ++j)
                        acc[i][j] = fmaf(a[i], b[j], acc[i][j]);
            }
        }

        // epilogue: score + per-thread top-5 update (fully unrolled, registers only)
#pragma unroll
        for (int j = 0; j < 4; ++j) {
            int tcol = c0 + s + tx * 4 + j;
            float tt = t2[tcol];
#pragma unroll
            for (int i = 0; i < 4; ++i) {
                float dd = fmaf(-2.0f, acc[i][j], tt);
                if (dd < bd[i][KNN - 1]) {
                    float nd = dd; int ni = tcol;
#pragma unroll
                    for (int k = 0; k < KNN; ++k) {
                        bool sw = (nd < bd[i][k]) || (nd == bd[i][k] && ni < bi_[i][k]);
                        float od = bd[i][k]; int oi = bi_[i][k];
                        bd[i][k] = sw ? nd : od; bi_[i][k] = sw ? ni : oi;
                        nd = sw ? od : nd;       ni = sw ? oi : ni;
                    }
                }
            }
        }
    }

    // ---- block merge: 16 tx-threads x 5 candidates per query ----
    __syncthreads();   // done with Xs/Ts; reuse as MD/MI
#pragma unroll
    for (int i = 0; i < 4; ++i)
#pragma unroll
        for (int k = 0; k < KNN; ++k) {
            MD[ty * 4 + i][tx * KNN + k] = bd[i][k];
            MI[ty * 4 + i][tx * KNN + k] = bi_[i][k];
        }
    __syncthreads();
    if (tid < QT) {
        int q = q0 + tid;
        for (int k = 0; k < KNN; ++k) {
            float best = 3.4e38f; int bidx = 0x7fffffff; int bj = -1;
            for (int j = 0; j < 16 * KNN; ++j) {
                float dv = MD[tid][j]; int iv = MI[tid][j];
                if (dv < best || (dv == best && iv < bidx)) { best = dv; bidx = iv; bj = j; }
            }
            MD[tid][bj] = 3.4e38f;
            candD[((size_t)q * NCHUNK + blockIdx.y) * KNN + k] = best;
            candI[((size_t)q * NCHUNK + blockIdx.y) * KNN + k] = bidx;
        }
    }
}

// ---------------- kernel C: final merge + label vote ----------------
__global__ __launch_bounds__(256)
void knn_final(const float* __restrict__ candD, const int* __restrict__ candI,
               const int* __restrict__ y, int* __restrict__ out) {
    int q = blockIdx.x * 256 + threadIdx.x;
    if (q >= NQ) return;

    // detect int64 vs int32 label storage (int64 -> odd 32-bit words are 0)
    bool is64 = true;
#pragma unroll
    for (int i = 1; i < 64; i += 2) is64 = is64 && (y[i] == 0);

    float bd[KNN]; int bi_[KNN];
#pragma unroll
    for (int k = 0; k < KNN; ++k) { bd[k] = 3.4e38f; bi_[k] = 0x7fffffff; }

    for (int c = 0; c < NCHUNK * KNN; ++c) {
        float dv = candD[(size_t)q * NCHUNK * KNN + c];
        int   iv = candI[(size_t)q * NCHUNK * KNN + c];
        if (dv < bd[KNN - 1] || (dv == bd[KNN - 1] && iv < bi_[KNN - 1])) {
            float nd = dv; int ni = iv;
#pragma unroll
            for (int k = 0; k < KNN; ++k) {
                bool sw = (nd < bd[k]) || (nd == bd[k] && ni < bi_[k]);
                float od = bd[k]; int oi = bi_[k];
                bd[k] = sw ? nd : od; bi_[k] = sw ? ni : oi;
                nd = sw ? od : nd;    ni = sw ? oi : ni;
            }
        }
    }

    int lab[KNN];
#pragma unroll
    for (int k = 0; k < KNN; ++k) lab[k] = is64 ? y[2 * bi_[k]] : y[bi_[k]];

    int bestLab = 0x7fffffff, bestC = 0;
#pragma unroll
    for (int i = 0; i < KNN; ++i) {
        int c = 0;
#pragma unroll
        for (int j = 0; j < KNN; ++j) c += (lab[j] == lab[i]);
        if (c > bestC || (c == bestC && lab[i] < bestLab)) { bestC = c; bestLab = lab[i]; }
    }
    out[q] = bestLab;
}

extern "C" void kernel_launch(void* const* d_in, const int* in_sizes, int n_in,
                              void* d_out, int out_size, void* d_ws, size_t ws_size,
                              hipStream_t stream) {
    const float* x  = (const float*)d_in[0];
    const float* xt = (const float*)d_in[1];
    const int*   y  = (const int*)d_in[2];

    float* ws    = (float*)d_ws;
    float* t2    = ws;                                   // 65536 floats
    float* candD = ws + NTRAIN;                          // 2048*32*5 floats
    int*   candI = (int*)(ws + NTRAIN + (size_t)NQ * NCHUNK * KNN);
    int*   out   = (int*)d_out;

    hipLaunchKernelGGL(t2_kernel, dim3(NTRAIN / 4), dim3(256), 0, stream, xt, t2);
    hipLaunchKernelGGL(knn_partial, dim3(NQT, NCHUNK), dim3(256), 0, stream,
                       x, xt, t2, candD, candI);
    hipLaunchKernelGGL(knn_final, dim3(NQ / 256), dim3(256), 0, stream,
                       candD, candI, y, out);
}

// Round 4
// 759.647 us; speedup vs baseline: 3.5958x; 3.5958x over previous
//
#include <hip/hip_runtime.h>

#define NTRAIN 65536
#define NQ     2048
#define KD     512
#define KNN    5

// ---------------- filter GEMM tiles ----------------
#define BM 128           // train rows per block (= chunk)
#define BN 128           // queries per block
#define BK 32
#define NCH (NTRAIN / BM)        // 512 chunks
#define MARGIN 2.0f
#define CAP 128

typedef short short8 __attribute__((ext_vector_type(8)));
typedef float f32x4 __attribute__((ext_vector_type(4)));

__device__ inline unsigned short f2bf(float f) {
    unsigned u = __float_as_uint(f);
    unsigned r = u + 0x7fffu + ((u >> 16) & 1u);
    return (unsigned short)(r >> 16);
}

template<int KK>
__device__ inline void ins5(float (&bd)[KK], int (&bi)[KK], float nd, int ni) {
    if (nd < bd[KK-1] || (nd == bd[KK-1] && ni < bi[KK-1])) {
#pragma unroll
        for (int k = 0; k < KK; ++k) {
            bool sw = (nd < bd[k]) || (nd == bd[k] && ni < bi[k]);
            float od = bd[k]; int oi = bi[k];
            bd[k] = sw ? nd : od; bi[k] = sw ? ni : oi;
            nd = sw ? od : nd;    ni = sw ? oi : ni;
        }
    }
}

// value-only top-5 insert (duplicates preserved)
__device__ inline void ins5v(float (&b5)[KNN], float v) {
    if (v < b5[KNN-1]) {
#pragma unroll
        for (int k = 0; k < KNN; ++k) {
            bool sw = v < b5[k];
            float o = b5[k];
            b5[k] = sw ? v : o;
            v = sw ? o : v;
        }
    }
}

// ---------------- t2: EXACT round-1 arithmetic ----------------
__global__ __launch_bounds__(256)
void t2_kernel(const float* __restrict__ xt, float* __restrict__ t2) {
    int row  = blockIdx.x * 4 + (threadIdx.x >> 6);
    int lane = threadIdx.x & 63;
    const float4* p = (const float4*)(xt + (size_t)row * KD);
    float s = 0.f;
#pragma unroll
    for (int c = 0; c < 2; ++c) {
        float4 v = p[lane + c * 64];
        s += v.x * v.x + v.y * v.y + v.z * v.z + v.w * v.w;
    }
#pragma unroll
    for (int off = 32; off; off >>= 1) s += __shfl_down(s, off);
    if (lane == 0) t2[row] = s;
}

// ---------------- bf16 conversion kernels ----------------
__global__ __launch_bounds__(256)
void conv_x_kernel(const float* __restrict__ in, unsigned short* __restrict__ out) {
    int i = blockIdx.x * 256 + threadIdx.x;           // 8 elems per thread
    const float4* p = (const float4*)in + (size_t)i * 2;
    float4 v0 = p[0], v1 = p[1];
    unsigned short us[8] = { f2bf(v0.x), f2bf(v0.y), f2bf(v0.z), f2bf(v0.w),
                             f2bf(v1.x), f2bf(v1.y), f2bf(v1.z), f2bf(v1.w) };
    *(uint4*)(out + (size_t)i * 8) = *(const uint4*)us;
}

__global__ __launch_bounds__(256)
void conv_xt_kernel(const float* __restrict__ xt, unsigned short* __restrict__ xtb) {
    int row  = blockIdx.x * 4 + (threadIdx.x >> 6);
    int lane = threadIdx.x & 63;
    const float4* p = (const float4*)(xt + (size_t)row * KD) + lane * 2;
    float4 v0 = p[0], v1 = p[1];
    unsigned short us[8] = { f2bf(v0.x), f2bf(v0.y), f2bf(v0.z), f2bf(v0.w),
                             f2bf(v1.x), f2bf(v1.y), f2bf(v1.z), f2bf(v1.w) };
    *(uint4*)(xtb + (size_t)row * KD + lane * 8) = *(const uint4*)us;
}

// ---------------- filter: MFMA GEMM + fused per-chunk top-5 ----------------
__global__ __launch_bounds__(256)
void knn_filter(const unsigned short* __restrict__ xb, const unsigned short* __restrict__ xtb,
                const float* __restrict__ t2,
                float* __restrict__ candD, int* __restrict__ candI) {
    __shared__ __align__(16) char smem[40960];   // staging 16KB | merge 40KB (aliased)

    const int tid  = threadIdx.x;
    const int w    = tid >> 6, lane = tid & 63;
    const int wm   = w & 1,  wn = w >> 1;
    const int q0   = blockIdx.x * BN;
    const int c0   = blockIdx.y * BM;

    const int ua0 = tid, ua1 = tid + 256;
    const int ra0 = ((ua0 >> 6) << 4) | (ua0 & 15), ka0 = (ua0 >> 4) & 3;
    const int ra1 = ((ua1 >> 6) << 4) | (ua1 & 15), ka1 = (ua1 >> 4) & 3;

    const unsigned short* Abase = xtb + (size_t)c0 * KD;
    const unsigned short* Bbase = xb  + (size_t)q0 * KD;

    short8 pa0 = *(const short8*)(Abase + (size_t)ra0 * KD + ka0 * 8);
    short8 pa1 = *(const short8*)(Abase + (size_t)ra1 * KD + ka1 * 8);
    short8 pb0 = *(const short8*)(Bbase + (size_t)ra0 * KD + ka0 * 8);
    short8 pb1 = *(const short8*)(Bbase + (size_t)ra1 * KD + ka1 * 8);

    f32x4 acc[4][4];
#pragma unroll
    for (int m = 0; m < 4; ++m)
#pragma unroll
        for (int n = 0; n < 4; ++n) acc[m][n] = 0.f;

    for (int kt = 0; kt < KD; kt += BK) {
        __syncthreads();
        *(short8*)(smem + ua0 * 16)        = pa0;
        *(short8*)(smem + ua1 * 16)        = pa1;
        *(short8*)(smem + 8192 + ua0 * 16) = pb0;
        *(short8*)(smem + 8192 + ua1 * 16) = pb1;
        if (kt + BK < KD) {
            pa0 = *(const short8*)(Abase + (size_t)ra0 * KD + kt + BK + ka0 * 8);
            pa1 = *(const short8*)(Abase + (size_t)ra1 * KD + kt + BK + ka1 * 8);
            pb0 = *(const short8*)(Bbase + (size_t)ra0 * KD + kt + BK + ka0 * 8);
            pb1 = *(const short8*)(Bbase + (size_t)ra1 * KD + kt + BK + ka1 * 8);
        }
        __syncthreads();
        short8 a[4], b[4];
#pragma unroll
        for (int m = 0; m < 4; ++m)
            a[m] = *(const short8*)(smem + ((wm * 4 + m) * 64 + lane) * 16);
#pragma unroll
        for (int n = 0; n < 4; ++n)
            b[n] = *(const short8*)(smem + 8192 + ((wn * 4 + n) * 64 + lane) * 16);
#pragma unroll
        for (int m = 0; m < 4; ++m)
#pragma unroll
            for (int n = 0; n < 4; ++n)
                acc[m][n] = __builtin_amdgcn_mfma_f32_16x16x32_bf16(a[m], b[n], acc[m][n], 0, 0, 0);
    }

    // epilogue: score + per-lane per-query top-5
    const int rb = c0 + wm * 64 + ((lane >> 4) << 2);   // + m*16 + r
    float t2v[4][4];
#pragma unroll
    for (int m = 0; m < 4; ++m)
#pragma unroll
        for (int r = 0; r < 4; ++r) t2v[m][r] = t2[rb + m * 16 + r];

    float bd[4][KNN]; int bi[4][KNN];
#pragma unroll
    for (int n = 0; n < 4; ++n)
#pragma unroll
        for (int k = 0; k < KNN; ++k) { bd[n][k] = 3.4e38f; bi[n][k] = 0x7fffffff; }

#pragma unroll
    for (int n = 0; n < 4; ++n)
#pragma unroll
        for (int m = 0; m < 4; ++m)
#pragma unroll
            for (int r = 0; r < 4; ++r) {
                float s = fmaf(-2.f, acc[m][n][r], t2v[m][r]);
                ins5(bd[n], bi[n], s, rb + m * 16 + r);
            }

    __syncthreads();                              // done with staging LDS -> merge buffers
    float* MD = (float*)smem;                     // [128][40]
    int*   MI = (int*)(smem + 20480);
    const int slot = wm * 4 + (lane >> 4);        // 0..7 contributors per query
#pragma unroll
    for (int n = 0; n < 4; ++n) {
        int ql = wn * 64 + n * 16 + (lane & 15);
#pragma unroll
        for (int k = 0; k < KNN; ++k) {
            MD[ql * 40 + slot * KNN + k] = bd[n][k];
            MI[ql * 40 + slot * KNN + k] = bi[n][k];
        }
    }
    __syncthreads();
    if (tid < BN) {
        float fd[KNN]; int fi[KNN];
#pragma unroll
        for (int k = 0; k < KNN; ++k) { fd[k] = 3.4e38f; fi[k] = 0x7fffffff; }
        for (int j = 0; j < 40; ++j) ins5(fd, fi, MD[tid * 40 + j], MI[tid * 40 + j]);
        size_t base = ((size_t)(q0 + tid) * NCH + blockIdx.y) * KNN;
#pragma unroll
        for (int k = 0; k < KNN; ++k) { candD[base + k] = fd[k]; candI[base + k] = fi[k]; }
    }
}

// ---------------- refine: TRUE global approx top-5 -> tight T -> exact rerank -> vote ----
__global__ __launch_bounds__(256)
void knn_refine(const float* __restrict__ x, const float* __restrict__ xt,
                const float* __restrict__ t2,
                const float* __restrict__ candD, const int* __restrict__ candI,
                const int* __restrict__ y, int* __restrict__ out) {
    __shared__ float sv[256 * KNN];   // stage-1 per-thread top-5 values
    __shared__ float sv2[64 * KNN];   // stage-2
    __shared__ float xl[KD];
    __shared__ int   lidx[CAP];
    __shared__ float lex[CAP];
    __shared__ int   lcount;
    __shared__ float sT;

    const int q = blockIdx.x, tid = threadIdx.x;
    const float* cd = candD + (size_t)q * NCH * KNN;
    const int*   ci = candI + (size_t)q * NCH * KNN;

    for (int i = tid; i < KD; i += 256) xl[i] = x[(size_t)q * KD + i];

    // ---- stage 1: per-thread top-5 over strided subset (values only) ----
    float b5[KNN];
#pragma unroll
    for (int k = 0; k < KNN; ++k) b5[k] = 3.4e38f;
    for (int j = tid; j < NCH * KNN; j += 256) ins5v(b5, cd[j]);
#pragma unroll
    for (int k = 0; k < KNN; ++k) sv[tid * KNN + k] = b5[k];
    __syncthreads();

    // ---- stage 2: 64 threads merge 4 lists each ----
    if (tid < 64) {
#pragma unroll
        for (int k = 0; k < KNN; ++k) b5[k] = 3.4e38f;
        for (int t = 0; t < 4; ++t)
#pragma unroll
            for (int k = 0; k < KNN; ++k) ins5v(b5, sv[(tid * 4 + t) * KNN + k]);
#pragma unroll
        for (int k = 0; k < KNN; ++k) sv2[tid * KNN + k] = b5[k];
    }
    __syncthreads();

    // ---- stage 3: thread 0 merges 64 lists -> a5 (exact global approx 5th) ----
    if (tid == 0) {
#pragma unroll
        for (int k = 0; k < KNN; ++k) b5[k] = 3.4e38f;
        for (int j = 0; j < 64 * KNN; ++j) ins5v(b5, sv2[j]);
        sT = b5[KNN - 1] + MARGIN;     // a5 + margin: superset bound needs only 2*eps_bf16
        lcount = 0;
    }
    __syncthreads();
    float T = sT;

    for (int j = tid; j < NCH * KNN; j += 256) {
        if (cd[j] <= T) {
            int p = atomicAdd(&lcount, 1);
            if (p < CAP) lidx[p] = ci[j];
        }
    }
    __syncthreads();
    int Q = min(lcount, CAP);

    // exact rerank: one thread per candidate, sequential fmaf over k (round-1 order)
    for (int j = tid; j < Q; j += 256) {
        int c = lidx[j];
        const float* tr = xt + (size_t)c * KD;
        float s = 0.f;
        for (int k = 0; k < KD; ++k) s = fmaf(xl[k], tr[k], s);
        lex[j] = fmaf(-2.f, s, t2[c]);
    }
    __syncthreads();

    if (tid == 0) {
        bool is64 = true;
#pragma unroll
        for (int i = 1; i < 64; i += 2) is64 = is64 && (y[i] == 0);
        float fd[KNN]; int fi[KNN];
#pragma unroll
        for (int k = 0; k < KNN; ++k) { fd[k] = 3.4e38f; fi[k] = 0x7fffffff; }
        for (int j = 0; j < Q; ++j) ins5(fd, fi, lex[j], lidx[j]);
        int lab[KNN];
#pragma unroll
        for (int k = 0; k < KNN; ++k) lab[k] = is64 ? y[2 * fi[k]] : y[fi[k]];
        int bestLab = 0x7fffffff, bestC = 0;
#pragma unroll
        for (int i = 0; i < KNN; ++i) {
            int c = 0;
#pragma unroll
            for (int j = 0; j < KNN; ++j) c += (lab[j] == lab[i]);
            if (c > bestC || (c == bestC && lab[i] < bestLab)) { bestC = c; bestLab = lab[i]; }
        }
        out[q] = bestLab;
    }
}

// =================== round-1 fp32 fallback (small ws) ===================
#define FB_QT 64
#define FB_TT 64
#define FB_KT 32
#define FB_NCHUNK 32
#define FB_CHUNK (NTRAIN / FB_NCHUNK)

__global__ __launch_bounds__(256)
void fb_knn_partial(const float* __restrict__ x, const float* __restrict__ xt,
                    const float* __restrict__ t2,
                    float* __restrict__ candD, int* __restrict__ candI) {
    __shared__ __align__(16) float smem[FB_QT * 81 * 2];
    float (*Xs)[FB_QT + 4] = (float (*)[FB_QT + 4])smem;
    float (*Ts)[FB_TT + 4] = (float (*)[FB_TT + 4])(smem + FB_KT * (FB_QT + 4));
    float (*MD)[81]     = (float (*)[81])smem;
    int   (*MI)[81]     = (int   (*)[81])(smem + FB_QT * 81);

    const int tid = threadIdx.x;
    const int tx = tid & 15, ty = tid >> 4;
    const int q0 = blockIdx.x * FB_QT;
    const int c0 = blockIdx.y * FB_CHUNK;
    const int sq = tid >> 2, sc = tid & 3;

    float bd[4][KNN]; int bi_[4][KNN];
#pragma unroll
    for (int i = 0; i < 4; ++i)
#pragma unroll
        for (int k = 0; k < KNN; ++k) { bd[i][k] = 3.4e38f; bi_[i][k] = 0x7fffffff; }

    const float* xrow = x + (size_t)(q0 + sq) * KD;

    for (int s = 0; s < FB_CHUNK; s += FB_TT) {
        float acc[4][4];
#pragma unroll
        for (int i = 0; i < 4; ++i)
#pragma unroll
            for (int j = 0; j < 4; ++j) acc[i][j] = 0.f;
        const float* trow = xt + (size_t)(c0 + s + sq) * KD;
        for (int kt = 0; kt < KD; kt += FB_KT) {
            float4 xv0 = *(const float4*)(xrow + kt + sc * 8);
            float4 xv1 = *(const float4*)(xrow + kt + sc * 8 + 4);
            float4 tv0 = *(const float4*)(trow + kt + sc * 8);
            float4 tv1 = *(const float4*)(trow + kt + sc * 8 + 4);
            __syncthreads();
            Xs[sc*8+0][sq] = xv0.x; Xs[sc*8+1][sq] = xv0.y;
            Xs[sc*8+2][sq] = xv0.z; Xs[sc*8+3][sq] = xv0.w;
            Xs[sc*8+4][sq] = xv1.x; Xs[sc*8+5][sq] = xv1.y;
            Xs[sc*8+6][sq] = xv1.z; Xs[sc*8+7][sq] = xv1.w;
            Ts[sc*8+0][sq] = tv0.x; Ts[sc*8+1][sq] = tv0.y;
            Ts[sc*8+2][sq] = tv0.z; Ts[sc*8+3][sq] = tv0.w;
            Ts[sc*8+4][sq] = tv1.x; Ts[sc*8+5][sq] = tv1.y;
            Ts[sc*8+6][sq] = tv1.z; Ts[sc*8+7][sq] = tv1.w;
            __syncthreads();
#pragma unroll
            for (int k = 0; k < FB_KT; ++k) {
                const float4 av = *(const float4*)&Xs[k][ty * 4];
                const float4 bv = *(const float4*)&Ts[k][tx * 4];
                float a[4] = {av.x, av.y, av.z, av.w};
                float b[4] = {bv.x, bv.y, bv.z, bv.w};
#pragma unroll
                for (int i = 0; i < 4; ++i)
#pragma unroll
                    for (int j = 0; j < 4; ++j)
                        acc[i][j] = fmaf(a[i], b[j], acc[i][j]);
            }
        }
#pragma unroll
        for (int j = 0; j < 4; ++j) {
            int tcol = c0 + s + tx * 4 + j;
            float tt = t2[tcol];
#pragma unroll
            for (int i = 0; i < 4; ++i)
                ins5(bd[i], bi_[i], fmaf(-2.0f, acc[i][j], tt), tcol);
        }
    }
    __syncthreads();
#pragma unroll
    for (int i = 0; i < 4; ++i)
#pragma unroll
        for (int k = 0; k < KNN; ++k) {
            MD[ty * 4 + i][tx * KNN + k] = bd[i][k];
            MI[ty * 4 + i][tx * KNN + k] = bi_[i][k];
        }
    __syncthreads();
    if (tid < FB_QT) {
        int q = q0 + tid;
        for (int k = 0; k < KNN; ++k) {
            float best = 3.4e38f; int bidx = 0x7fffffff; int bj = -1;
            for (int j = 0; j < 16 * KNN; ++j) {
                float dv = MD[tid][j]; int iv = MI[tid][j];
                if (dv < best || (dv == best && iv < bidx)) { best = dv; bidx = iv; bj = j; }
            }
            MD[tid][bj] = 3.4e38f;
            candD[((size_t)q * FB_NCHUNK + blockIdx.y) * KNN + k] = best;
            candI[((size_t)q * FB_NCHUNK + blockIdx.y) * KNN + k] = bidx;
        }
    }
}

__global__ __launch_bounds__(256)
void fb_knn_final(const float* __restrict__ candD, const int* __restrict__ candI,
                  const int* __restrict__ y, int* __restrict__ out) {
    int q = blockIdx.x * 256 + threadIdx.x;
    if (q >= NQ) return;
    bool is64 = true;
#pragma unroll
    for (int i = 1; i < 64; i += 2) is64 = is64 && (y[i] == 0);
    float bd[KNN]; int bi_[KNN];
#pragma unroll
    for (int k = 0; k < KNN; ++k) { bd[k] = 3.4e38f; bi_[k] = 0x7fffffff; }
    for (int c = 0; c < FB_NCHUNK * KNN; ++c)
        ins5(bd, bi_, candD[(size_t)q * FB_NCHUNK * KNN + c], candI[(size_t)q * FB_NCHUNK * KNN + c]);
    int lab[KNN];
#pragma unroll
    for (int k = 0; k < KNN; ++k) lab[k] = is64 ? y[2 * bi_[k]] : y[bi_[k]];
    int bestLab = 0x7fffffff, bestC = 0;
#pragma unroll
    for (int i = 0; i < KNN; ++i) {
        int c = 0;
#pragma unroll
        for (int j = 0; j < KNN; ++j) c += (lab[j] == lab[i]);
        if (c > bestC || (c == bestC && lab[i] < bestLab)) { bestC = c; bestLab = lab[i]; }
    }
    out[q] = bestLab;
}

// =================== launch ===================
extern "C" void kernel_launch(void* const* d_in, const int* in_sizes, int n_in,
                              void* d_out, int out_size, void* d_ws, size_t ws_size,
                              hipStream_t stream) {
    const float* x  = (const float*)d_in[0];
    const float* xt = (const float*)d_in[1];
    const int*   y  = (const int*)d_in[2];
    int* out = (int*)d_out;

    const size_t REQ = 111411200ull;
    if (ws_size >= REQ) {
        char* ws = (char*)d_ws;
        unsigned short* xt_bf = (unsigned short*)ws;                       // 67,108,864
        unsigned short* x_bf  = (unsigned short*)(ws + 67108864);          //  2,097,152
        float*          t2    = (float*)(ws + 69206016);                   //    262,144
        float*          candD = (float*)(ws + 69468160);                   // 20,971,520
        int*            candI = (int*)(ws + 90439680);                     // 20,971,520

        hipLaunchKernelGGL(t2_kernel, dim3(NTRAIN / 4), dim3(256), 0, stream, xt, t2);
        hipLaunchKernelGGL(conv_x_kernel, dim3(NQ * KD / 8 / 256), dim3(256), 0, stream, x, x_bf);
        hipLaunchKernelGGL(conv_xt_kernel, dim3(NTRAIN / 4), dim3(256), 0, stream, xt, xt_bf);
        hipLaunchKernelGGL(knn_filter, dim3(NQ / BN, NTRAIN / BM), dim3(256), 0, stream,
                           x_bf, xt_bf, t2, candD, candI);
        hipLaunchKernelGGL(knn_refine, dim3(NQ), dim3(256), 0, stream,
                           x, xt, t2, candD, candI, y, out);
    } else {
        float* ws    = (float*)d_ws;
        float* t2    = ws;
        float* candD = ws + NTRAIN;
        int*   candI = (int*)(ws + NTRAIN + (size_t)NQ * FB_NCHUNK * KNN);
        hipLaunchKernelGGL(t2_kernel, dim3(NTRAIN / 4), dim3(256), 0, stream, xt, t2);
        hipLaunchKernelGGL(fb_knn_partial, dim3(NQ / FB_QT, FB_NCHUNK), dim3(256), 0, stream,
                           x, xt, t2, candD, candI);
        hipLaunchKernelGGL(fb_knn_final, dim3(NQ / 256), dim3(256), 0, stream,
                           candD, candI, y, out);
    }
}

// Round 5
// 641.654 us; speedup vs baseline: 4.2570x; 1.1839x over previous
//
#include <hip/hip_runtime.h>

#define NTRAIN 65536
#define NQ     2048
#define KD     512
#define KNN    5

// ---------------- filter GEMM config ----------------
#define BM 128                   // train rows per chunk
#define BN 128                   // queries per block
#define BK 32                    // K step
#define CPB 4                    // chunks per block
#define GROUP (BM * CPB)         // 512 train rows per block
#define NCG (NTRAIN / GROUP)     // 128 chunk-groups
#define NQT (NQ / BN)            // 16 query tiles
#define NSTEP ((KD / BK) * CPB)  // 64 pipeline steps per block
#define MARGIN 2.0f
#define CAP 128

typedef short short8 __attribute__((ext_vector_type(8)));
typedef float f32x4 __attribute__((ext_vector_type(4)));

__device__ inline unsigned short f2bf(float f) {
    unsigned u = __float_as_uint(f);
    unsigned r = u + 0x7fffu + ((u >> 16) & 1u);
    return (unsigned short)(r >> 16);
}

template<int KK>
__device__ inline void ins5(float (&bd)[KK], int (&bi)[KK], float nd, int ni) {
    if (nd < bd[KK-1] || (nd == bd[KK-1] && ni < bi[KK-1])) {
#pragma unroll
        for (int k = 0; k < KK; ++k) {
            bool sw = (nd < bd[k]) || (nd == bd[k] && ni < bi[k]);
            float od = bd[k]; int oi = bi[k];
            bd[k] = sw ? nd : od; bi[k] = sw ? ni : oi;
            nd = sw ? od : nd;    ni = sw ? oi : ni;
        }
    }
}

__device__ inline void ins5v(float (&b5)[KNN], float v) {
    if (v < b5[KNN-1]) {
#pragma unroll
        for (int k = 0; k < KNN; ++k) {
            bool sw = v < b5[k];
            float o = b5[k];
            b5[k] = sw ? v : o;
            v = sw ? o : v;
        }
    }
}

// async global->LDS, 16B per lane; LDS dest = wave-uniform base + lane*16
__device__ inline void gload16(const void* g, void* l) {
    __builtin_amdgcn_global_load_lds(
        (const __attribute__((address_space(1))) void*)g,
        (__attribute__((address_space(3))) void*)l,
        16, 0, 0);
}

// ---------------- t2 (round-1 arithmetic) fused with xt bf16 conversion ----------------
__global__ __launch_bounds__(256)
void conv_xt_t2_kernel(const float* __restrict__ xt, unsigned short* __restrict__ xtb,
                       float* __restrict__ t2) {
    int row  = blockIdx.x * 4 + (threadIdx.x >> 6);
    int lane = threadIdx.x & 63;
    const float4* p = (const float4*)(xt + (size_t)row * KD);
    float s = 0.f;
#pragma unroll
    for (int c = 0; c < 2; ++c) {
        float4 v = p[lane + c * 64];
        s += v.x * v.x + v.y * v.y + v.z * v.z + v.w * v.w;
        unsigned short us[4] = { f2bf(v.x), f2bf(v.y), f2bf(v.z), f2bf(v.w) };
        *(unsigned long long*)(xtb + (size_t)row * KD + (size_t)(lane + c * 64) * 4) =
            *(const unsigned long long*)us;
    }
#pragma unroll
    for (int off = 32; off; off >>= 1) s += __shfl_down(s, off);
    if (lane == 0) t2[row] = s;
}

__global__ __launch_bounds__(256)
void conv_x_kernel(const float* __restrict__ in, unsigned short* __restrict__ out) {
    int i = blockIdx.x * 256 + threadIdx.x;           // 8 elems per thread
    const float4* p = (const float4*)in + (size_t)i * 2;
    float4 v0 = p[0], v1 = p[1];
    unsigned short us[8] = { f2bf(v0.x), f2bf(v0.y), f2bf(v0.z), f2bf(v0.w),
                             f2bf(v1.x), f2bf(v1.y), f2bf(v1.z), f2bf(v1.w) };
    *(uint4*)(out + (size_t)i * 8) = *(const uint4*)us;
}

// ---------------- filter: pipelined MFMA GEMM, 4 chunks/block, fused top-5 ----------------
// LDS unit layout (identical to verified round-4 mapping):
//   frag f, lane l -> row = f*16 + (l&15), k = (l>>4)*8 .. +8, at offset f*1024 + l*16
__global__ __launch_bounds__(256)
void knn_filter(const unsigned short* __restrict__ xb, const unsigned short* __restrict__ xtb,
                const float* __restrict__ t2,
                float* __restrict__ candD, int* __restrict__ candI) {
    __shared__ __align__(16) char smem[40960];   // staging 2x16KB | merge 40KB (aliased)

    const int tid  = threadIdx.x;
    const int w    = tid >> 6, lane = tid & 63;
    const int wm   = w & 1,  wn = w >> 1;

    // bijective XCD swizzle: all 16 query-tiles of one chunk-group land on one XCD,
    // and each XCD walks its chunk-groups sequentially (L2-resident 2MB A-panel).
    const int b   = blockIdx.x;
    const int xcd = b & 7;
    const int r   = b >> 3;
    const int qt  = r & 15;
    const int cg  = xcd + 8 * (r >> 4);

    const int q0   = qt * BN;
    const int row0 = cg * GROUP;

    const int lrow = lane & 15;
    const int lk   = (lane >> 4) * 8;

    const unsigned short* Ab = xtb + (size_t)row0 * KD;
    const unsigned short* Bb = xb  + (size_t)q0  * KD;

    f32x4 acc[4][4];
#pragma unroll
    for (int m = 0; m < 4; ++m)
#pragma unroll
        for (int n = 0; n < 4; ++n) acc[m][n] = 0.f;

    float bd[4][KNN]; int bi[4][KNN];
#pragma unroll
    for (int n = 0; n < 4; ++n)
#pragma unroll
        for (int k = 0; k < KNN; ++k) { bd[n][k] = 3.4e38f; bi[n][k] = 0x7fffffff; }

    // prologue: stage step 0 into buffer 0
    {
        char* bufA = smem;
        char* bufB = smem + 8192;
#pragma unroll
        for (int i = 0; i < 2; ++i) {
            int f = 2 * w + i;
            gload16(Ab + (size_t)(f * 16 + lrow) * KD + lk, bufA + f * 1024);
            gload16(Bb + (size_t)(f * 16 + lrow) * KD + lk, bufB + f * 1024);
        }
    }
    __syncthreads();

    int cur = 0;
    for (int s = 0; s < NSTEP; ++s) {
        // issue next-step staging first (loads stay in flight under ds_read+MFMA)
        if (s + 1 < NSTEP) {
            const int s1 = s + 1;
            const int ch = s1 >> 4;
            const int kt = (s1 & 15) * BK;
            const unsigned short* Asrc = Ab + (size_t)ch * BM * KD;
            char* bufA = smem + (cur ^ 1) * 16384;
            char* bufB = bufA + 8192;
#pragma unroll
            for (int i = 0; i < 2; ++i) {
                int f = 2 * w + i;
                gload16(Asrc + (size_t)(f * 16 + lrow) * KD + kt + lk, bufA + f * 1024);
                gload16(Bb   + (size_t)(f * 16 + lrow) * KD + kt + lk, bufB + f * 1024);
            }
        }

        // compute current buffer
        const char* bufA = smem + cur * 16384;
        const char* bufB = bufA + 8192;
        short8 a[4], bfr[4];
#pragma unroll
        for (int m = 0; m < 4; ++m)
            a[m] = *(const short8*)(bufA + ((wm * 4 + m) * 64 + lane) * 16);
#pragma unroll
        for (int n = 0; n < 4; ++n)
            bfr[n] = *(const short8*)(bufB + ((wn * 4 + n) * 64 + lane) * 16);
#pragma unroll
        for (int m = 0; m < 4; ++m)
#pragma unroll
            for (int n = 0; n < 4; ++n)
                acc[m][n] = __builtin_amdgcn_mfma_f32_16x16x32_bf16(a[m], bfr[n], acc[m][n], 0, 0, 0);

        // per-chunk epilogue: fold scores into persistent top-5, reset acc
        if ((s & 15) == 15) {
            const int ch = s >> 4;
            const int c0 = row0 + ch * BM;
            const int rb = c0 + wm * 64 + ((lane >> 4) << 2);
            float t2v[4][4];
#pragma unroll
            for (int m = 0; m < 4; ++m)
#pragma unroll
                for (int r2 = 0; r2 < 4; ++r2) t2v[m][r2] = t2[rb + m * 16 + r2];
#pragma unroll
            for (int n = 0; n < 4; ++n)
#pragma unroll
                for (int m = 0; m < 4; ++m)
#pragma unroll
                    for (int r2 = 0; r2 < 4; ++r2) {
                        float sc = fmaf(-2.f, acc[m][n][r2], t2v[m][r2]);
                        ins5(bd[n], bi[n], sc, rb + m * 16 + r2);
                    }
#pragma unroll
            for (int m = 0; m < 4; ++m)
#pragma unroll
                for (int n = 0; n < 4; ++n) acc[m][n] = 0.f;
        }

        __syncthreads();   // drains staging (vmcnt) + guards buffer reuse
        cur ^= 1;
    }

    // ---- block merge (once per block, covers all 4 chunks) ----
    float* MD = (float*)smem;                     // [128][40]
    int*   MI = (int*)(smem + 20480);
    const int slot = wm * 4 + (lane >> 4);        // 8 contributors per query
#pragma unroll
    for (int n = 0; n < 4; ++n) {
        int ql = wn * 64 + n * 16 + (lane & 15);
#pragma unroll
        for (int k = 0; k < KNN; ++k) {
            MD[ql * 40 + slot * KNN + k] = bd[n][k];
            MI[ql * 40 + slot * KNN + k] = bi[n][k];
        }
    }
    __syncthreads();
    if (tid < BN) {
        float fd[KNN]; int fi[KNN];
#pragma unroll
        for (int k = 0; k < KNN; ++k) { fd[k] = 3.4e38f; fi[k] = 0x7fffffff; }
        for (int j = 0; j < 40; ++j) ins5(fd, fi, MD[tid * 40 + j], MI[tid * 40 + j]);
        size_t base = ((size_t)(q0 + tid) * NCG + cg) * KNN;
#pragma unroll
        for (int k = 0; k < KNN; ++k) { candD[base + k] = fd[k]; candI[base + k] = fi[k]; }
    }
}

// ---------------- refine: global approx top-5 -> tight T -> exact rerank -> vote ----------
__global__ __launch_bounds__(256)
void knn_refine(const float* __restrict__ x, const float* __restrict__ xt,
                const float* __restrict__ t2,
                const float* __restrict__ candD, const int* __restrict__ candI,
                const int* __restrict__ y, int* __restrict__ out) {
    __shared__ float sv[256 * KNN];
    __shared__ float sv2[64 * KNN];
    __shared__ float xl[KD];
    __shared__ int   lidx[CAP];
    __shared__ float lex[CAP];
    __shared__ int   lcount;
    __shared__ float sT;

    const int q = blockIdx.x, tid = threadIdx.x;
    const float* cd = candD + (size_t)q * NCG * KNN;
    const int*   ci = candI + (size_t)q * NCG * KNN;

    for (int i = tid; i < KD; i += 256) xl[i] = x[(size_t)q * KD + i];

    // stage 1: per-thread top-5 (values only)
    float b5[KNN];
#pragma unroll
    for (int k = 0; k < KNN; ++k) b5[k] = 3.4e38f;
    for (int j = tid; j < NCG * KNN; j += 256) ins5v(b5, cd[j]);
#pragma unroll
    for (int k = 0; k < KNN; ++k) sv[tid * KNN + k] = b5[k];
    __syncthreads();

    // stage 2: 64 threads merge 4 lists each
    if (tid < 64) {
#pragma unroll
        for (int k = 0; k < KNN; ++k) b5[k] = 3.4e38f;
        for (int t = 0; t < 4; ++t)
#pragma unroll
            for (int k = 0; k < KNN; ++k) ins5v(b5, sv[(tid * 4 + t) * KNN + k]);
#pragma unroll
        for (int k = 0; k < KNN; ++k) sv2[tid * KNN + k] = b5[k];
    }
    __syncthreads();

    // stage 3: exact global approx 5th -> threshold
    if (tid == 0) {
#pragma unroll
        for (int k = 0; k < KNN; ++k) b5[k] = 3.4e38f;
        for (int j = 0; j < 64 * KNN; ++j) ins5v(b5, sv2[j]);
        sT = b5[KNN - 1] + MARGIN;
        lcount = 0;
    }
    __syncthreads();
    float T = sT;

    for (int j = tid; j < NCG * KNN; j += 256) {
        if (cd[j] <= T) {
            int p = atomicAdd(&lcount, 1);
            if (p < CAP) lidx[p] = ci[j];
        }
    }
    __syncthreads();
    int Q = min(lcount, CAP);

    // exact rerank: one thread per candidate, sequential fmaf over k (round-1 order)
    for (int j = tid; j < Q; j += 256) {
        int c = lidx[j];
        const float* tr = xt + (size_t)c * KD;
        float s = 0.f;
        for (int k = 0; k < KD; ++k) s = fmaf(xl[k], tr[k], s);
        lex[j] = fmaf(-2.f, s, t2[c]);
    }
    __syncthreads();

    if (tid == 0) {
        bool is64 = true;
#pragma unroll
        for (int i = 1; i < 64; i += 2) is64 = is64 && (y[i] == 0);
        float fd[KNN]; int fi[KNN];
#pragma unroll
        for (int k = 0; k < KNN; ++k) { fd[k] = 3.4e38f; fi[k] = 0x7fffffff; }
        for (int j = 0; j < Q; ++j) ins5(fd, fi, lex[j], lidx[j]);
        int lab[KNN];
#pragma unroll
        for (int k = 0; k < KNN; ++k) lab[k] = is64 ? y[2 * fi[k]] : y[fi[k]];
        int bestLab = 0x7fffffff, bestC = 0;
#pragma unroll
        for (int i = 0; i < KNN; ++i) {
            int c = 0;
#pragma unroll
            for (int j = 0; j < KNN; ++j) c += (lab[j] == lab[i]);
            if (c > bestC || (c == bestC && lab[i] < bestLab)) { bestC = c; bestLab = lab[i]; }
        }
        out[q] = bestLab;
    }
}

// =================== round-1 fp32 fallback (small ws) ===================
#define FB_QT 64
#define FB_TT 64
#define FB_KT 32
#define FB_NCHUNK 32
#define FB_CHUNK (NTRAIN / FB_NCHUNK)

__global__ __launch_bounds__(256)
void t2_kernel(const float* __restrict__ xt, float* __restrict__ t2) {
    int row  = blockIdx.x * 4 + (threadIdx.x >> 6);
    int lane = threadIdx.x & 63;
    const float4* p = (const float4*)(xt + (size_t)row * KD);
    float s = 0.f;
#pragma unroll
    for (int c = 0; c < 2; ++c) {
        float4 v = p[lane + c * 64];
        s += v.x * v.x + v.y * v.y + v.z * v.z + v.w * v.w;
    }
#pragma unroll
    for (int off = 32; off; off >>= 1) s += __shfl_down(s, off);
    if (lane == 0) t2[row] = s;
}

__global__ __launch_bounds__(256)
void fb_knn_partial(const float* __restrict__ x, const float* __restrict__ xt,
                    const float* __restrict__ t2,
                    float* __restrict__ candD, int* __restrict__ candI) {
    __shared__ __align__(16) float smem[FB_QT * 81 * 2];
    float (*Xs)[FB_QT + 4] = (float (*)[FB_QT + 4])smem;
    float (*Ts)[FB_TT + 4] = (float (*)[FB_TT + 4])(smem + FB_KT * (FB_QT + 4));
    float (*MD)[81]     = (float (*)[81])smem;
    int   (*MI)[81]     = (int   (*)[81])(smem + FB_QT * 81);

    const int tid = threadIdx.x;
    const int tx = tid & 15, ty = tid >> 4;
    const int q0 = blockIdx.x * FB_QT;
    const int c0 = blockIdx.y * FB_CHUNK;
    const int sq = tid >> 2, sc = tid & 3;

    float bd[4][KNN]; int bi_[4][KNN];
#pragma unroll
    for (int i = 0; i < 4; ++i)
#pragma unroll
        for (int k = 0; k < KNN; ++k) { bd[i][k] = 3.4e38f; bi_[i][k] = 0x7fffffff; }

    const float* xrow = x + (size_t)(q0 + sq) * KD;

    for (int s = 0; s < FB_CHUNK; s += FB_TT) {
        float acc[4][4];
#pragma unroll
        for (int i = 0; i < 4; ++i)
#pragma unroll
            for (int j = 0; j < 4; ++j) acc[i][j] = 0.f;
        const float* trow = xt + (size_t)(c0 + s + sq) * KD;
        for (int kt = 0; kt < KD; kt += FB_KT) {
            float4 xv0 = *(const float4*)(xrow + kt + sc * 8);
            float4 xv1 = *(const float4*)(xrow + kt + sc * 8 + 4);
            float4 tv0 = *(const float4*)(trow + kt + sc * 8);
            float4 tv1 = *(const float4*)(trow + kt + sc * 8 + 4);
            __syncthreads();
            Xs[sc*8+0][sq] = xv0.x; Xs[sc*8+1][sq] = xv0.y;
            Xs[sc*8+2][sq] = xv0.z; Xs[sc*8+3][sq] = xv0.w;
            Xs[sc*8+4][sq] = xv1.x; Xs[sc*8+5][sq] = xv1.y;
            Xs[sc*8+6][sq] = xv1.z; Xs[sc*8+7][sq] = xv1.w;
            Ts[sc*8+0][sq] = tv0.x; Ts[sc*8+1][sq] = tv0.y;
            Ts[sc*8+2][sq] = tv0.z; Ts[sc*8+3][sq] = tv0.w;
            Ts[sc*8+4][sq] = tv1.x; Ts[sc*8+5][sq] = tv1.y;
            Ts[sc*8+6][sq] = tv1.z; Ts[sc*8+7][sq] = tv1.w;
            __syncthreads();
#pragma unroll
            for (int k = 0; k < FB_KT; ++k) {
                const float4 av = *(const float4*)&Xs[k][ty * 4];
                const float4 bv = *(const float4*)&Ts[k][tx * 4];
                float a[4] = {av.x, av.y, av.z, av.w};
                float b[4] = {bv.x, bv.y, bv.z, bv.w};
#pragma unroll
                for (int i = 0; i < 4; ++i)
#pragma unroll
                    for (int j = 0; j < 4; ++j)
                        acc[i][j] = fmaf(a[i], b[j], acc[i][j]);
            }
        }
#pragma unroll
        for (int j = 0; j < 4; ++j) {
            int tcol = c0 + s + tx * 4 + j;
            float tt = t2[tcol];
#pragma unroll
            for (int i = 0; i < 4; ++i)
                ins5(bd[i], bi_[i], fmaf(-2.0f, acc[i][j], tt), tcol);
        }
    }
    __syncthreads();
#pragma unroll
    for (int i = 0; i < 4; ++i)
#pragma unroll
        for (int k = 0; k < KNN; ++k) {
            MD[ty * 4 + i][tx * KNN + k] = bd[i][k];
            MI[ty * 4 + i][tx * KNN + k] = bi_[i][k];
        }
    __syncthreads();
    if (tid < FB_QT) {
        int q = q0 + tid;
        for (int k = 0; k < KNN; ++k) {
            float best = 3.4e38f; int bidx = 0x7fffffff; int bj = -1;
            for (int j = 0; j < 16 * KNN; ++j) {
                float dv = MD[tid][j]; int iv = MI[tid][j];
                if (dv < best || (dv == best && iv < bidx)) { best = dv; bidx = iv; bj = j; }
            }
            MD[tid][bj] = 3.4e38f;
            candD[((size_t)q * FB_NCHUNK + blockIdx.y) * KNN + k] = best;
            candI[((size_t)q * FB_NCHUNK + blockIdx.y) * KNN + k] = bidx;
        }
    }
}

__global__ __launch_bounds__(256)
void fb_knn_final(const float* __restrict__ candD, const int* __restrict__ candI,
                  const int* __restrict__ y, int* __restrict__ out) {
    int q = blockIdx.x * 256 + threadIdx.x;
    if (q >= NQ) return;
    bool is64 = true;
#pragma unroll
    for (int i = 1; i < 64; i += 2) is64 = is64 && (y[i] == 0);
    float bd[KNN]; int bi_[KNN];
#pragma unroll
    for (int k = 0; k < KNN; ++k) { bd[k] = 3.4e38f; bi_[k] = 0x7fffffff; }
    for (int c = 0; c < FB_NCHUNK * KNN; ++c)
        ins5(bd, bi_, candD[(size_t)q * FB_NCHUNK * KNN + c], candI[(size_t)q * FB_NCHUNK * KNN + c]);
    int lab[KNN];
#pragma unroll
    for (int k = 0; k < KNN; ++k) lab[k] = is64 ? y[2 * bi_[k]] : y[bi_[k]];
    int bestLab = 0x7fffffff, bestC = 0;
#pragma unroll
    for (int i = 0; i < KNN; ++i) {
        int c = 0;
#pragma unroll
        for (int j = 0; j < KNN; ++j) c += (lab[j] == lab[i]);
        if (c > bestC || (c == bestC && lab[i] < bestLab)) { bestC = c; bestLab = lab[i]; }
    }
    out[q] = bestLab;
}

// =================== launch ===================
extern "C" void kernel_launch(void* const* d_in, const int* in_sizes, int n_in,
                              void* d_out, int out_size, void* d_ws, size_t ws_size,
                              hipStream_t stream) {
    const float* x  = (const float*)d_in[0];
    const float* xt = (const float*)d_in[1];
    const int*   y  = (const int*)d_in[2];
    int* out = (int*)d_out;

    // layout: xt_bf 64MB | x_bf 2MB | t2 256KB | candD 5.25MB | candI 5.25MB
    const size_t REQ = 79953920ull;
    if (ws_size >= REQ) {
        char* ws = (char*)d_ws;
        unsigned short* xt_bf = (unsigned short*)ws;
        unsigned short* x_bf  = (unsigned short*)(ws + 67108864);
        float*          t2    = (float*)(ws + 69206016);
        float*          candD = (float*)(ws + 69468160);
        int*            candI = (int*)(ws + 74711040);

        hipLaunchKernelGGL(conv_xt_t2_kernel, dim3(NTRAIN / 4), dim3(256), 0, stream, xt, xt_bf, t2);
        hipLaunchKernelGGL(conv_x_kernel, dim3(NQ * KD / 8 / 256), dim3(256), 0, stream, x, x_bf);
        hipLaunchKernelGGL(knn_filter, dim3(NQT * NCG), dim3(256), 0, stream,
                           x_bf, xt_bf, t2, candD, candI);
        hipLaunchKernelGGL(knn_refine, dim3(NQ), dim3(256), 0, stream,
                           x, xt, t2, candD, candI, y, out);
    } else {
        float* ws    = (float*)d_ws;
        float* t2    = ws;
        float* candD = ws + NTRAIN;
        int*   candI = (int*)(ws + NTRAIN + (size_t)NQ * FB_NCHUNK * KNN);
        hipLaunchKernelGGL(t2_kernel, dim3(NTRAIN / 4), dim3(256), 0, stream, xt, t2);
        hipLaunchKernelGGL(fb_knn_partial, dim3(NQ / FB_QT, FB_NCHUNK), dim3(256), 0, stream,
                           x, xt, t2, candD, candI);
        hipLaunchKernelGGL(fb_knn_final, dim3(NQ / 256), dim3(256), 0, stream,
                           candD, candI, y, out);
    }
}

// Round 6
// 628.762 us; speedup vs baseline: 4.3443x; 1.0205x over previous
//
#include <hip/hip_runtime.h>

#define NTRAIN 65536
#define NQ     2048
#define KD     512
#define KNN    5

// ---------------- filter GEMM config ----------------
#define BM 128                   // train rows per chunk
#define BN 128                   // queries per block
#define BK 32                    // K step
#define CPB 4                    // chunks per block
#define GROUP (BM * CPB)         // 512 train rows per block
#define NCG (NTRAIN / GROUP)     // 128 chunk-groups
#define NQT (NQ / BN)            // 16 query tiles
#define NSTEP ((KD / BK) * CPB)  // 64 pipeline steps per block
#define MARGIN 2.0f
#define CAP 128

#define STEPBYTES 16384          // A 8KB + B 8KB per step
#define NBUF 3                   // rotating staging buffers
#define T2OFF (STEPBYTES * NBUF) // t2 LDS offset (49152)
#define SMEMSZ (T2OFF + GROUP * 4)  // 51200

typedef short short8 __attribute__((ext_vector_type(8)));
typedef float f32x4 __attribute__((ext_vector_type(4)));

__device__ inline unsigned short f2bf(float f) {
    unsigned u = __float_as_uint(f);
    unsigned r = u + 0x7fffu + ((u >> 16) & 1u);
    return (unsigned short)(r >> 16);
}

template<int KK>
__device__ inline void ins5(float (&bd)[KK], int (&bi)[KK], float nd, int ni) {
    if (nd < bd[KK-1] || (nd == bd[KK-1] && ni < bi[KK-1])) {
#pragma unroll
        for (int k = 0; k < KK; ++k) {
            bool sw = (nd < bd[k]) || (nd == bd[k] && ni < bi[k]);
            float od = bd[k]; int oi = bi[k];
            bd[k] = sw ? nd : od; bi[k] = sw ? ni : oi;
            nd = sw ? od : nd;    ni = sw ? oi : ni;
        }
    }
}

__device__ inline void ins5v(float (&b5)[KNN], float v) {
    if (v < b5[KNN-1]) {
#pragma unroll
        for (int k = 0; k < KNN; ++k) {
            bool sw = v < b5[k];
            float o = b5[k];
            b5[k] = sw ? v : o;
            v = sw ? o : v;
        }
    }
}

// async global->LDS, 16B per lane; LDS dest = wave-uniform base + lane*16
__device__ inline void gload16(const void* g, void* l) {
    __builtin_amdgcn_global_load_lds(
        (const __attribute__((address_space(1))) void*)g,
        (__attribute__((address_space(3))) void*)l,
        16, 0, 0);
}

// ---------------- t2 (round-1 arithmetic) fused with xt bf16 conversion ----------------
__global__ __launch_bounds__(256)
void conv_xt_t2_kernel(const float* __restrict__ xt, unsigned short* __restrict__ xtb,
                       float* __restrict__ t2) {
    int row  = blockIdx.x * 4 + (threadIdx.x >> 6);
    int lane = threadIdx.x & 63;
    const float4* p = (const float4*)(xt + (size_t)row * KD);
    float s = 0.f;
#pragma unroll
    for (int c = 0; c < 2; ++c) {
        float4 v = p[lane + c * 64];
        s += v.x * v.x + v.y * v.y + v.z * v.z + v.w * v.w;
        unsigned short us[4] = { f2bf(v.x), f2bf(v.y), f2bf(v.z), f2bf(v.w) };
        *(unsigned long long*)(xtb + (size_t)row * KD + (size_t)(lane + c * 64) * 4) =
            *(const unsigned long long*)us;
    }
#pragma unroll
    for (int off = 32; off; off >>= 1) s += __shfl_down(s, off);
    if (lane == 0) t2[row] = s;
}

__global__ __launch_bounds__(256)
void conv_x_kernel(const float* __restrict__ in, unsigned short* __restrict__ out) {
    int i = blockIdx.x * 256 + threadIdx.x;           // 8 elems per thread
    const float4* p = (const float4*)in + (size_t)i * 2;
    float4 v0 = p[0], v1 = p[1];
    unsigned short us[8] = { f2bf(v0.x), f2bf(v0.y), f2bf(v0.z), f2bf(v0.w),
                             f2bf(v1.x), f2bf(v1.y), f2bf(v1.z), f2bf(v1.w) };
    *(uint4*)(out + (size_t)i * 8) = *(const uint4*)us;
}

// ---------------- filter: counted-vmcnt pipelined MFMA GEMM, 4 chunks/block ----------------
// LDS unit layout (verified): frag f, lane l -> row=f*16+(l&15), k=(l>>4)*8.., off f*1024+l*16
__global__ __launch_bounds__(256)
void knn_filter(const unsigned short* __restrict__ xb, const unsigned short* __restrict__ xtb,
                const float* __restrict__ t2g,
                float* __restrict__ candD, int* __restrict__ candI) {
    __shared__ __align__(16) char smem[SMEMSZ];

    const int tid  = threadIdx.x;
    const int w    = tid >> 6, lane = tid & 63;
    const int wm   = w & 1,  wn = w >> 1;

    // bijective XCD swizzle: 16 query-tiles of one chunk-group share an XCD
    const int b   = blockIdx.x;
    const int xcd = b & 7;
    const int r   = b >> 3;
    const int qt  = r & 15;
    const int cg  = xcd + 8 * (r >> 4);

    const int q0   = qt * BN;
    const int row0 = cg * GROUP;

    const int lrow = lane & 15;
    const int lk   = (lane >> 4) * 8;

    const unsigned short* Ab = xtb + (size_t)row0 * KD;
    const unsigned short* Bb = xb  + (size_t)q0  * KD;

    const int f0 = 2 * w, f1 = 2 * w + 1;
    const size_t offL0 = (size_t)(f0 * 16 + lrow) * KD + lk;   // per-lane element offset
    const size_t offL1 = (size_t)(f1 * 16 + lrow) * KD + lk;
    float* t2s = (float*)(smem + T2OFF);

    f32x4 acc[4][4];
#pragma unroll
    for (int m = 0; m < 4; ++m)
#pragma unroll
        for (int n = 0; n < 4; ++n) acc[m][n] = 0.f;

    float bd[4][KNN]; int bi[4][KNN];
#pragma unroll
    for (int n = 0; n < 4; ++n)
#pragma unroll
        for (int k = 0; k < KNN; ++k) { bd[n][k] = 3.4e38f; bi[n][k] = 0x7fffffff; }

    // prologue A: t2 -> LDS (completed + visible before any prefetch is in flight)
    {
        float tv0 = t2g[row0 + tid];
        float tv1 = t2g[row0 + 256 + tid];
        t2s[tid] = tv0; t2s[256 + tid] = tv1;
    }
    __syncthreads();   // full drain (only t2 in flight) + t2s visibility

    // prologue B: issue steps 0 and 1 (8 gloads/thread in flight)
    {
        char* b0 = smem;
        gload16(Ab + offL0,      b0 + f0 * 1024);
        gload16(Bb + offL0,      b0 + 8192 + f0 * 1024);
        gload16(Ab + offL1,      b0 + f1 * 1024);
        gload16(Bb + offL1,      b0 + 8192 + f1 * 1024);
        char* b1 = smem + STEPBYTES;
        gload16(Ab + BK + offL0, b1 + f0 * 1024);
        gload16(Bb + BK + offL0, b1 + 8192 + f0 * 1024);
        gload16(Ab + BK + offL1, b1 + f1 * 1024);
        gload16(Bb + BK + offL1, b1 + 8192 + f1 * 1024);
    }

    int rd = 0;        // s % 3
    int wr = 2;        // (s+2) % 3
    for (int s = 0; s < NSTEP; ++s) {
        // counted wait: keep the newest 4 loads (step s+1) in flight across the barrier
        if (s < NSTEP - 1) asm volatile("s_waitcnt vmcnt(4)" ::: "memory");
        else               asm volatile("s_waitcnt vmcnt(0)" ::: "memory");
        __builtin_amdgcn_s_barrier();
        __builtin_amdgcn_sched_barrier(0);

        // issue step s+2 (2 steps ahead; lands 2 barriers later)
        if (s + 2 < NSTEP) {
            const int s2 = s + 2;
            const unsigned short* Asrc = Ab + (size_t)(s2 >> 4) * (BM * KD) + (s2 & 15) * BK;
            const unsigned short* Bsrc = Bb + (s2 & 15) * BK;
            char* bA = smem + wr * STEPBYTES;
            gload16(Asrc + offL0, bA + f0 * 1024);
            gload16(Bsrc + offL0, bA + 8192 + f0 * 1024);
            gload16(Asrc + offL1, bA + f1 * 1024);
            gload16(Bsrc + offL1, bA + 8192 + f1 * 1024);
        }

        // compute current buffer
        const char* bufA = smem + rd * STEPBYTES;
        const char* bufB = bufA + 8192;
        short8 a[4], bfr[4];
#pragma unroll
        for (int m = 0; m < 4; ++m)
            a[m] = *(const short8*)(bufA + ((wm * 4 + m) * 64 + lane) * 16);
#pragma unroll
        for (int n = 0; n < 4; ++n)
            bfr[n] = *(const short8*)(bufB + ((wn * 4 + n) * 64 + lane) * 16);
#pragma unroll
        for (int m = 0; m < 4; ++m)
#pragma unroll
            for (int n = 0; n < 4; ++n)
                acc[m][n] = __builtin_amdgcn_mfma_f32_16x16x32_bf16(a[m], bfr[n], acc[m][n], 0, 0, 0);

        // per-chunk epilogue: fold into persistent top-5 (t2 from LDS: no vmcnt pollution)
        if ((s & 15) == 15) {
            const int ch  = s >> 4;
            const int rbl = wm * 64 + ((lane >> 4) << 2);      // local row in chunk
            const int c0  = row0 + ch * BM;
            float4 t2v[4];
#pragma unroll
            for (int m = 0; m < 4; ++m)
                t2v[m] = *(const float4*)(t2s + ch * BM + rbl + m * 16);
#pragma unroll
            for (int n = 0; n < 4; ++n)
#pragma unroll
                for (int m = 0; m < 4; ++m)
#pragma unroll
                    for (int r2 = 0; r2 < 4; ++r2) {
                        float sc = fmaf(-2.f, acc[m][n][r2], (&t2v[m].x)[r2]);
                        ins5(bd[n], bi[n], sc, c0 + rbl + m * 16 + r2);
                    }
#pragma unroll
            for (int m = 0; m < 4; ++m)
#pragma unroll
                for (int n = 0; n < 4; ++n) acc[m][n] = 0.f;
        }

        rd = (rd == 2) ? 0 : rd + 1;
        wr = (wr == 2) ? 0 : wr + 1;
    }

    __syncthreads();   // all waves done with staging LDS before merge reuses it

    // ---- block merge (once per block, covers all 4 chunks) ----
    float* MD = (float*)smem;                     // [128][40]
    int*   MI = (int*)(smem + 20480);
    const int slot = wm * 4 + (lane >> 4);        // 8 contributors per query
#pragma unroll
    for (int n = 0; n < 4; ++n) {
        int ql = wn * 64 + n * 16 + (lane & 15);
#pragma unroll
        for (int k = 0; k < KNN; ++k) {
            MD[ql * 40 + slot * KNN + k] = bd[n][k];
            MI[ql * 40 + slot * KNN + k] = bi[n][k];
        }
    }
    __syncthreads();
    if (tid < BN) {
        float fd[KNN]; int fi[KNN];
#pragma unroll
        for (int k = 0; k < KNN; ++k) { fd[k] = 3.4e38f; fi[k] = 0x7fffffff; }
        for (int j = 0; j < 40; ++j) ins5(fd, fi, MD[tid * 40 + j], MI[tid * 40 + j]);
        size_t base = ((size_t)(q0 + tid) * NCG + cg) * KNN;
#pragma unroll
        for (int k = 0; k < KNN; ++k) { candD[base + k] = fd[k]; candI[base + k] = fi[k]; }
    }
}

// ---------------- refine: global approx top-5 -> tight T -> exact rerank -> vote ----------
__global__ __launch_bounds__(256)
void knn_refine(const float* __restrict__ x, const float* __restrict__ xt,
                const float* __restrict__ t2,
                const float* __restrict__ candD, const int* __restrict__ candI,
                const int* __restrict__ y, int* __restrict__ out) {
    __shared__ float sv[256 * KNN];
    __shared__ float sv2[64 * KNN];
    __shared__ float xl[KD];
    __shared__ int   lidx[CAP];
    __shared__ float lex[CAP];
    __shared__ int   lcount;
    __shared__ float sT;

    const int q = blockIdx.x, tid = threadIdx.x;
    const float* cd = candD + (size_t)q * NCG * KNN;
    const int*   ci = candI + (size_t)q * NCG * KNN;

    for (int i = tid; i < KD; i += 256) xl[i] = x[(size_t)q * KD + i];

    // stage 1: per-thread top-5 (values only)
    float b5[KNN];
#pragma unroll
    for (int k = 0; k < KNN; ++k) b5[k] = 3.4e38f;
    for (int j = tid; j < NCG * KNN; j += 256) ins5v(b5, cd[j]);
#pragma unroll
    for (int k = 0; k < KNN; ++k) sv[tid * KNN + k] = b5[k];
    __syncthreads();

    // stage 2: 64 threads merge 4 lists each
    if (tid < 64) {
#pragma unroll
        for (int k = 0; k < KNN; ++k) b5[k] = 3.4e38f;
        for (int t = 0; t < 4; ++t)
#pragma unroll
            for (int k = 0; k < KNN; ++k) ins5v(b5, sv[(tid * 4 + t) * KNN + k]);
#pragma unroll
        for (int k = 0; k < KNN; ++k) sv2[tid * KNN + k] = b5[k];
    }
    __syncthreads();

    // stage 3: exact global approx 5th -> threshold
    if (tid == 0) {
#pragma unroll
        for (int k = 0; k < KNN; ++k) b5[k] = 3.4e38f;
        for (int j = 0; j < 64 * KNN; ++j) ins5v(b5, sv2[j]);
        sT = b5[KNN - 1] + MARGIN;
        lcount = 0;
    }
    __syncthreads();
    float T = sT;

    for (int j = tid; j < NCG * KNN; j += 256) {
        if (cd[j] <= T) {
            int p = atomicAdd(&lcount, 1);
            if (p < CAP) lidx[p] = ci[j];
        }
    }
    __syncthreads();
    int Q = min(lcount, CAP);

    // exact rerank: one thread per candidate, sequential fmaf over k (round-1 order)
    for (int j = tid; j < Q; j += 256) {
        int c = lidx[j];
        const float* tr = xt + (size_t)c * KD;
        float s = 0.f;
        for (int k = 0; k < KD; ++k) s = fmaf(xl[k], tr[k], s);
        lex[j] = fmaf(-2.f, s, t2[c]);
    }
    __syncthreads();

    if (tid == 0) {
        bool is64 = true;
#pragma unroll
        for (int i = 1; i < 64; i += 2) is64 = is64 && (y[i] == 0);
        float fd[KNN]; int fi[KNN];
#pragma unroll
        for (int k = 0; k < KNN; ++k) { fd[k] = 3.4e38f; fi[k] = 0x7fffffff; }
        for (int j = 0; j < Q; ++j) ins5(fd, fi, lex[j], lidx[j]);
        int lab[KNN];
#pragma unroll
        for (int k = 0; k < KNN; ++k) lab[k] = is64 ? y[2 * fi[k]] : y[fi[k]];
        int bestLab = 0x7fffffff, bestC = 0;
#pragma unroll
        for (int i = 0; i < KNN; ++i) {
            int c = 0;
#pragma unroll
            for (int j = 0; j < KNN; ++j) c += (lab[j] == lab[i]);
            if (c > bestC || (c == bestC && lab[i] < bestLab)) { bestC = c; bestLab = lab[i]; }
        }
        out[q] = bestLab;
    }
}

// =================== round-1 fp32 fallback (small ws) ===================
#define FB_QT 64
#define FB_TT 64
#define FB_KT 32
#define FB_NCHUNK 32
#define FB_CHUNK (NTRAIN / FB_NCHUNK)

__global__ __launch_bounds__(256)
void t2_kernel(const float* __restrict__ xt, float* __restrict__ t2) {
    int row  = blockIdx.x * 4 + (threadIdx.x >> 6);
    int lane = threadIdx.x & 63;
    const float4* p = (const float4*)(xt + (size_t)row * KD);
    float s = 0.f;
#pragma unroll
    for (int c = 0; c < 2; ++c) {
        float4 v = p[lane + c * 64];
        s += v.x * v.x + v.y * v.y + v.z * v.z + v.w * v.w;
    }
#pragma unroll
    for (int off = 32; off; off >>= 1) s += __shfl_down(s, off);
    if (lane == 0) t2[row] = s;
}

__global__ __launch_bounds__(256)
void fb_knn_partial(const float* __restrict__ x, const float* __restrict__ xt,
                    const float* __restrict__ t2,
                    float* __restrict__ candD, int* __restrict__ candI) {
    __shared__ __align__(16) float smem[FB_QT * 81 * 2];
    float (*Xs)[FB_QT + 4] = (float (*)[FB_QT + 4])smem;
    float (*Ts)[FB_TT + 4] = (float (*)[FB_TT + 4])(smem + FB_KT * (FB_QT + 4));
    float (*MD)[81]     = (float (*)[81])smem;
    int   (*MI)[81]     = (int   (*)[81])(smem + FB_QT * 81);

    const int tid = threadIdx.x;
    const int tx = tid & 15, ty = tid >> 4;
    const int q0 = blockIdx.x * FB_QT;
    const int c0 = blockIdx.y * FB_CHUNK;
    const int sq = tid >> 2, sc = tid & 3;

    float bd[4][KNN]; int bi_[4][KNN];
#pragma unroll
    for (int i = 0; i < 4; ++i)
#pragma unroll
        for (int k = 0; k < KNN; ++k) { bd[i][k] = 3.4e38f; bi_[i][k] = 0x7fffffff; }

    const float* xrow = x + (size_t)(q0 + sq) * KD;

    for (int s = 0; s < FB_CHUNK; s += FB_TT) {
        float acc[4][4];
#pragma unroll
        for (int i = 0; i < 4; ++i)
#pragma unroll
            for (int j = 0; j < 4; ++j) acc[i][j] = 0.f;
        const float* trow = xt + (size_t)(c0 + s + sq) * KD;
        for (int kt = 0; kt < KD; kt += FB_KT) {
            float4 xv0 = *(const float4*)(xrow + kt + sc * 8);
            float4 xv1 = *(const float4*)(xrow + kt + sc * 8 + 4);
            float4 tv0 = *(const float4*)(trow + kt + sc * 8);
            float4 tv1 = *(const float4*)(trow + kt + sc * 8 + 4);
            __syncthreads();
            Xs[sc*8+0][sq] = xv0.x; Xs[sc*8+1][sq] = xv0.y;
            Xs[sc*8+2][sq] = xv0.z; Xs[sc*8+3][sq] = xv0.w;
            Xs[sc*8+4][sq] = xv1.x; Xs[sc*8+5][sq] = xv1.y;
            Xs[sc*8+6][sq] = xv1.z; Xs[sc*8+7][sq] = xv1.w;
            Ts[sc*8+0][sq] = tv0.x; Ts[sc*8+1][sq] = tv0.y;
            Ts[sc*8+2][sq] = tv0.z; Ts[sc*8+3][sq] = tv0.w;
            Ts[sc*8+4][sq] = tv1.x; Ts[sc*8+5][sq] = tv1.y;
            Ts[sc*8+6][sq] = tv1.z; Ts[sc*8+7][sq] = tv1.w;
            __syncthreads();
#pragma unroll
            for (int k = 0; k < FB_KT; ++k) {
                const float4 av = *(const float4*)&Xs[k][ty * 4];
                const float4 bv = *(const float4*)&Ts[k][tx * 4];
                float a[4] = {av.x, av.y, av.z, av.w};
                float b[4] = {bv.x, bv.y, bv.z, bv.w};
#pragma unroll
                for (int i = 0; i < 4; ++i)
#pragma unroll
                    for (int j = 0; j < 4; ++j)
                        acc[i][j] = fmaf(a[i], b[j], acc[i][j]);
            }
        }
#pragma unroll
        for (int j = 0; j < 4; ++j) {
            int tcol = c0 + s + tx * 4 + j;
            float tt = t2[tcol];
#pragma unroll
            for (int i = 0; i < 4; ++i)
                ins5(bd[i], bi_[i], fmaf(-2.0f, acc[i][j], tt), tcol);
        }
    }
    __syncthreads();
#pragma unroll
    for (int i = 0; i < 4; ++i)
#pragma unroll
        for (int k = 0; k < KNN; ++k) {
            MD[ty * 4 + i][tx * KNN + k] = bd[i][k];
            MI[ty * 4 + i][tx * KNN + k] = bi_[i][k];
        }
    __syncthreads();
    if (tid < FB_QT) {
        int q = q0 + tid;
        for (int k = 0; k < KNN; ++k) {
            float best = 3.4e38f; int bidx = 0x7fffffff; int bj = -1;
            for (int j = 0; j < 16 * KNN; ++j) {
                float dv = MD[tid][j]; int iv = MI[tid][j];
                if (dv < best || (dv == best && iv < bidx)) { best = dv; bidx = iv; bj = j; }
            }
            MD[tid][bj] = 3.4e38f;
            candD[((size_t)q * FB_NCHUNK + blockIdx.y) * KNN + k] = best;
            candI[((size_t)q * FB_NCHUNK + blockIdx.y) * KNN + k] = bidx;
        }
    }
}

__global__ __launch_bounds__(256)
void fb_knn_final(const float* __restrict__ candD, const int* __restrict__ candI,
                  const int* __restrict__ y, int* __restrict__ out) {
    int q = blockIdx.x * 256 + threadIdx.x;
    if (q >= NQ) return;
    bool is64 = true;
#pragma unroll
    for (int i = 1; i < 64; i += 2) is64 = is64 && (y[i] == 0);
    float bd[KNN]; int bi_[KNN];
#pragma unroll
    for (int k = 0; k < KNN; ++k) { bd[k] = 3.4e38f; bi_[k] = 0x7fffffff; }
    for (int c = 0; c < FB_NCHUNK * KNN; ++c)
        ins5(bd, bi_, candD[(size_t)q * FB_NCHUNK * KNN + c], candI[(size_t)q * FB_NCHUNK * KNN + c]);
    int lab[KNN];
#pragma unroll
    for (int k = 0; k < KNN; ++k) lab[k] = is64 ? y[2 * bi_[k]] : y[bi_[k]];
    int bestLab = 0x7fffffff, bestC = 0;
#pragma unroll
    for (int i = 0; i < KNN; ++i) {
        int c = 0;
#pragma unroll
        for (int j = 0; j < KNN; ++j) c += (lab[j] == lab[i]);
        if (c > bestC || (c == bestC && lab[i] < bestLab)) { bestC = c; bestLab = lab[i]; }
    }
    out[q] = bestLab;
}

// =================== launch ===================
extern "C" void kernel_launch(void* const* d_in, const int* in_sizes, int n_in,
                              void* d_out, int out_size, void* d_ws, size_t ws_size,
                              hipStream_t stream) {
    const float* x  = (const float*)d_in[0];
    const float* xt = (const float*)d_in[1];
    const int*   y  = (const int*)d_in[2];
    int* out = (int*)d_out;

    // layout: xt_bf 64MB | x_bf 2MB | t2 256KB | candD 5.25MB | candI 5.25MB
    const size_t REQ = 79953920ull;
    if (ws_size >= REQ) {
        char* ws = (char*)d_ws;
        unsigned short* xt_bf = (unsigned short*)ws;
        unsigned short* x_bf  = (unsigned short*)(ws + 67108864);
        float*          t2    = (float*)(ws + 69206016);
        float*          candD = (float*)(ws + 69468160);
        int*            candI = (int*)(ws + 74711040);

        hipLaunchKernelGGL(conv_xt_t2_kernel, dim3(NTRAIN / 4), dim3(256), 0, stream, xt, xt_bf, t2);
        hipLaunchKernelGGL(conv_x_kernel, dim3(NQ * KD / 8 / 256), dim3(256), 0, stream, x, x_bf);
        hipLaunchKernelGGL(knn_filter, dim3(NQT * NCG), dim3(256), 0, stream,
                           x_bf, xt_bf, t2, candD, candI);
        hipLaunchKernelGGL(knn_refine, dim3(NQ), dim3(256), 0, stream,
                           x, xt, t2, candD, candI, y, out);
    } else {
        float* ws    = (float*)d_ws;
        float* t2    = ws;
        float* candD = ws + NTRAIN;
        int*   candI = (int*)(ws + NTRAIN + (size_t)NQ * FB_NCHUNK * KNN);
        hipLaunchKernelGGL(t2_kernel, dim3(NTRAIN / 4), dim3(256), 0, stream, xt, t2);
        hipLaunchKernelGGL(fb_knn_partial, dim3(NQ / FB_QT, FB_NCHUNK), dim3(256), 0, stream,
                           x, xt, t2, candD, candI);
        hipLaunchKernelGGL(fb_knn_final, dim3(NQ / 256), dim3(256), 0, stream,
                           candD, candI, y, out);
    }
}